// Round 4
// baseline (210.544 us; speedup 1.0000x reference)
//
#include <hip/hip_runtime.h>
#include <hip/hip_bf16.h>
#include <cstdint>
#include <cstddef>

// Problem shape (fixed): x [B=16][N=2048][D=512] fp32
#define BB 16
#define NN 2048
#define DD 512

typedef _Float16 f16x8 __attribute__((ext_vector_type(8)));
typedef _Float16 f16x4 __attribute__((ext_vector_type(4)));
typedef float f32x4 __attribute__((ext_vector_type(4)));

// Async global->LDS, 16 B per lane. LDS dest = wave-uniform base + lane*16.
__device__ __forceinline__ void async_ld16(void* lds, const void* g) {
    __builtin_amdgcn_global_load_lds(
        (const __attribute__((address_space(1))) unsigned int*)(uintptr_t)g,
        (__attribute__((address_space(3))) unsigned int*)(uint32_t)(uintptr_t)lds,
        16, 0, 0);
}

#define VM_WAIT(n) asm volatile("s_waitcnt vmcnt(" #n ")" ::: "memory")
#define RAW_BAR()  do { asm volatile("" ::: "memory"); __builtin_amdgcn_s_barrier(); asm volatile("" ::: "memory"); } while (0)
// Barrier that orders LDS (lgkm) only: global stores/atomics keep draining in
// the background (no vmcnt(0) drain, unlike __syncthreads()).
#define LGKM_BAR() do { asm volatile("s_waitcnt lgkmcnt(0)" ::: "memory"); \
                        __builtin_amdgcn_s_barrier();                      \
                        __builtin_amdgcn_sched_barrier(0); } while (0)

// ---------------------------------------------------------------------------
// K1 (fused): read x ONCE. Per 64-row slab: norms, xhn (normalized fp16),
// vT (fp16 transpose), denom zero-init. grid (NN/64, BB), 256 threads.
// ---------------------------------------------------------------------------
__global__ __launch_bounds__(256) void k_prep(const float* __restrict__ x,
                                              _Float16* __restrict__ xhn,
                                              _Float16* __restrict__ vT,
                                              float* __restrict__ denom) {
    __shared__ _Float16 t[512 * 66];     // [d][j], pitch 66 halves
    const int tid = threadIdx.x, lane = tid & 63, w = tid >> 6;
    const int b = blockIdx.y, j0 = blockIdx.x * 64;
    if (tid < 64) denom[b * NN + j0 + tid] = 0.f;
    const float* xb = x + ((size_t)b * NN + j0) * DD;

    for (int rr = 0; rr < 16; ++rr) {
        const int jj = w * 16 + rr;                 // row within slab
        const float* xr = xb + (size_t)jj * DD;
        float4 a = ((const float4*)xr)[lane];       // d = 4*lane ..
        float4 c = ((const float4*)xr)[lane + 64];  // d = 256+4*lane ..
        float ss = a.x*a.x + a.y*a.y + a.z*a.z + a.w*a.w
                 + c.x*c.x + c.y*c.y + c.z*c.z + c.w*c.w;
        #pragma unroll
        for (int o = 1; o < 64; o <<= 1) ss += __shfl_xor(ss, o);
        const float rn = 1.0f / sqrtf(ss);
        // normalized fp16 row (coalesced 8B stores)
        _Float16* dst = xhn + ((size_t)b * NN + j0 + jj) * DD;
        f16x4 v0 = {(_Float16)(a.x*rn), (_Float16)(a.y*rn), (_Float16)(a.z*rn), (_Float16)(a.w*rn)};
        f16x4 v1 = {(_Float16)(c.x*rn), (_Float16)(c.y*rn), (_Float16)(c.z*rn), (_Float16)(c.w*rn)};
        *(f16x4*)(dst + 4 * lane) = v0;
        *(f16x4*)(dst + 256 + 4 * lane) = v1;
        // unnormalized fp16 into transposed LDS tile
        const int d0 = 4 * lane, d1 = 256 + 4 * lane;
        t[(d0 + 0) * 66 + jj] = (_Float16)a.x;
        t[(d0 + 1) * 66 + jj] = (_Float16)a.y;
        t[(d0 + 2) * 66 + jj] = (_Float16)a.z;
        t[(d0 + 3) * 66 + jj] = (_Float16)a.w;
        t[(d1 + 0) * 66 + jj] = (_Float16)c.x;
        t[(d1 + 1) * 66 + jj] = (_Float16)c.y;
        t[(d1 + 2) * 66 + jj] = (_Float16)c.z;
        t[(d1 + 3) * 66 + jj] = (_Float16)c.w;
    }
    LGKM_BAR();   // xhn global stores keep draining under the vT phase
    // store vT rows: 512 d x 8 chunks of 8 halves; 4B-aligned b32 LDS reads.
    #pragma unroll
    for (int it = 0; it < 16; ++it) {
        const int id = it * 256 + tid;
        const int d = id >> 3, ch = (id & 7) * 8;
        const uint32_t* tp = (const uint32_t*)&t[d * 66 + ch];
        uint4 v = {tp[0], tp[1], tp[2], tp[3]};
        *(uint4*)(vT + ((size_t)b * DD + d) * NN + j0 + ch) = v;
    }
}

// ---------------------------------------------------------------------------
// K2 REWRITE: W = exp( xhn xhn^T ), symmetric-triangular, 256x256 tiles.
// 8 waves (2Mx4N, per-wave 128x64 out), BK=64, 128 KiB dynamic-LDS dbuf,
// counted vmcnt(8) + raw barriers + setprio — verbatim k_pv loop structure
// (which removed k_pv from the top-5).  36 pairs/batch * 16 = 576 blocks,
// 1 block/CU, 2.25 rounds (vs 4.25 rounds of tiny 128^2 blocks before).
// Epilogue: register exp + row/col butterfly sums -> denom atomics;
// symmetric W store via LDS transpose in 128-col/row sub-phases (67.6 KB
// scratch overlaying the GEMM buffers).
// ---------------------------------------------------------------------------
__global__ __launch_bounds__(512, 2) void k_scores(const _Float16* __restrict__ xhn,
                                                   _Float16* __restrict__ W,
                                                   float* __restrict__ denom) {
    extern __shared__ _Float16 smem[];        // 2 x (A 16384 + B 16384) halves
    const int tid = threadIdx.x;
    const int lane = tid & 63, w = tid >> 6;  // 8 waves
    const int wr = w >> 2, wcol = w & 3;      // 2 x 4 wave grid
    const int m_ = lane & 15, quad = lane >> 4;

    // XCD swizzle over flat 576-block grid (576 = 8 * 72).
    const int swz = ((int)blockIdx.x % 8) * 72 + (int)blockIdx.x / 8;
    const int b = swz / 36;
    int rem = swz % 36, ti = 0, rowlen = NN / 256;
    while (rem >= rowlen) { rem -= rowlen; ++ti; --rowlen; }
    const int tj = ti + rem;
    const int I = ti * 256, J = tj * 256;
    const bool diag = (ti == tj);

    const _Float16* Ab = xhn + ((size_t)b * NN + I) * DD;
    const _Float16* Bb = xhn + ((size_t)b * NN + J) * DD;

    const int sub = lane >> 3;
    const int swc = (lane & 7) ^ sub;
    const _Float16* agl = Ab + (size_t)(w * 32 + sub) * DD + swc * 8;
    const _Float16* bgl = Bb + (size_t)(w * 32 + sub) * DD + swc * 8;

    f32x4 acc[8][4];
    #pragma unroll
    for (int i = 0; i < 8; ++i)
        #pragma unroll
        for (int j = 0; j < 4; ++j) acc[i][j] = (f32x4){0.f, 0.f, 0.f, 0.f};

#define S_STAGE(kb_) do {                                                     \
    _Float16* A_ = smem + (((kb_) & 1) << 15);                                \
    const int k0_ = (kb_) * 64;                                               \
    _Pragma("unroll")                                                         \
    for (int c = 0; c < 4; ++c) {                                             \
        async_ld16(&A_[(w * 32 + c * 8) * 64], agl + (size_t)c * 8 * DD + k0_); \
        async_ld16(&A_[16384 + (w * 32 + c * 8) * 64], bgl + (size_t)c * 8 * DD + k0_); \
    } } while (0)

#define S_COMPUTE(kb_) do {                                                   \
    const _Float16* As_ = smem + (((kb_) & 1) << 15);                         \
    const _Float16* Bs_ = As_ + 16384;                                        \
    _Pragma("unroll")                                                         \
    for (int kc = 0; kc < 2; ++kc) {                                          \
        f16x8 af[8], bf[4];                                                   \
        _Pragma("unroll")                                                     \
        for (int i = 0; i < 8; ++i) {                                         \
            const int R = wr * 128 + i * 16 + m_;                             \
            af[i] = *(const f16x8*)&As_[R * 64 + (((kc * 4 + quad) ^ (R & 7)) * 8)]; \
        }                                                                     \
        _Pragma("unroll")                                                     \
        for (int j = 0; j < 4; ++j) {                                         \
            const int Rb = wcol * 64 + j * 16 + m_;                           \
            bf[j] = *(const f16x8*)&Bs_[Rb * 64 + (((kc * 4 + quad) ^ (Rb & 7)) * 8)]; \
        }                                                                     \
        _Pragma("unroll")                                                     \
        for (int i = 0; i < 8; ++i)                                           \
            _Pragma("unroll")                                                 \
            for (int j = 0; j < 4; ++j)                                       \
                acc[i][j] = __builtin_amdgcn_mfma_f32_16x16x32_f16(af[i], bf[j], acc[i][j], 0, 0, 0); \
    } } while (0)

    S_STAGE(0); S_STAGE(1);
    for (int kb = 0; kb < DD / 64 - 1; ++kb) {
        VM_WAIT(8);                 // cur buffer's 8 loads done; next 8 in flight
        RAW_BAR();
        __builtin_amdgcn_s_setprio(1);
        S_COMPUTE(kb);
        __builtin_amdgcn_s_setprio(0);
        RAW_BAR();
        if (kb + 2 < DD / 64) S_STAGE(kb + 2);
    }
    VM_WAIT(0);
    RAW_BAR();
    __builtin_amdgcn_s_setprio(1);
    S_COMPUTE(DD / 64 - 1);
    __builtin_amdgcn_s_setprio(0);

    // ---- Epilogue: exp -> wq, register row/col sums -> denom atomics ----
    f16x4 wq[8][4];
    float colpart[4] = {0.f, 0.f, 0.f, 0.f};
    #pragma unroll
    for (int i = 0; i < 8; ++i) {
        float rp[4] = {0.f, 0.f, 0.f, 0.f};
        #pragma unroll
        for (int j = 0; j < 4; ++j) {
            #pragma unroll
            for (int r = 0; r < 4; ++r) {
                const float wv_ = __expf(acc[i][j][r]);
                wq[i][j][r] = (_Float16)wv_;
                rp[r] += wv_;
                colpart[j] += wv_;
            }
        }
        #pragma unroll
        for (int r = 0; r < 4; ++r) {
            float s = rp[r];
            s += __shfl_xor(s, 1);
            s += __shfl_xor(s, 2);
            s += __shfl_xor(s, 4);
            s += __shfl_xor(s, 8);
            if (m_ == 0)
                atomicAdd(&denom[b * NN + I + wr * 128 + i * 16 + quad * 4 + r], s);
        }
    }
    if (!diag) {
        #pragma unroll
        for (int j = 0; j < 4; ++j) {
            float s = colpart[j];
            s += __shfl_xor(s, 16);
            s += __shfl_xor(s, 32);
            if (quad == 0)
                atomicAdd(&denom[b * NN + J + wcol * 64 + j * 16 + m_], s);
        }
    }

    LGKM_BAR();   // all K-loop LDS reads done before scratch overwrite

    // ---- Phase 1: W(J,I) via column-major transpose, 128-col sub-phases ----
    // scratch: [128 cols][pitch 264 rows] halves = 67.6 KB (fits 128 KB LDS)
    _Float16* WtT = smem;
    #pragma unroll
    for (int s = 0; s < 2; ++s) {
        if ((wcol >> 1) == s) {       // waves owning cols [s*128, s*128+128)
            #pragma unroll
            for (int i = 0; i < 8; ++i) {
                const int rowb = wr * 128 + i * 16 + quad * 4;
                #pragma unroll
                for (int j = 0; j < 4; ++j) {
                    const int lc = (wcol & 1) * 64 + j * 16 + m_;   // col - s*128
                    *(f16x4*)&WtT[lc * 264 + rowb] = wq[i][j];
                }
            }
        }
        LGKM_BAR();
        {
            const int rr = tid >> 2, off = (tid & 3) * 64;
            _Float16* wg = W + ((size_t)b * NN + J + s * 128 + rr) * NN + I + off;
            const _Float16* wl = &WtT[rr * 264 + off];
            #pragma unroll
            for (int c = 0; c < 64; c += 8)
                *(uint4*)(wg + c) = *(const uint4*)(wl + c);
        }
        LGKM_BAR();
    }

    // ---- Phase 2 (off-diag): W(I,J) row-major, 128-row sub-phases ----
    if (!diag) {
        _Float16* Wt = smem;
        #pragma unroll
        for (int s = 0; s < 2; ++s) {
            if (wr == s) {            // waves owning rows [s*128, s*128+128)
                #pragma unroll
                for (int i = 0; i < 8; ++i) {
                    const int lr0 = i * 16 + quad * 4;   // rowb - s*128
                    #pragma unroll
                    for (int j = 0; j < 4; ++j) {
                        const int col = wcol * 64 + j * 16 + m_;
                        #pragma unroll
                        for (int r = 0; r < 4; ++r)
                            Wt[(lr0 + r) * 264 + col] = wq[i][j][r];
                    }
                }
            }
            LGKM_BAR();
            {
                const int rr = tid >> 2, off = (tid & 3) * 64;
                _Float16* wg = W + ((size_t)b * NN + I + s * 128 + rr) * NN + J + off;
                const _Float16* wl = &Wt[rr * 264 + off];
                #pragma unroll
                for (int c = 0; c < 64; c += 8)
                    *(uint4*)(wg + c) = *(const uint4*)(wl + c);
            }
            LGKM_BAR();
        }
    }
#undef S_STAGE
#undef S_COMPUTE
}

// ---------------------------------------------------------------------------
// K3: O = (W @ V) * (1/denom_i), fp32 out.  (unchanged from R3)
// 256x256 tile, 8 waves, BK=64, 128 KiB dynamic-LDS dbuf, counted vmcnt(8).
// ---------------------------------------------------------------------------
__global__ __launch_bounds__(512, 2) void k_pv(const _Float16* __restrict__ W,
                                               const _Float16* __restrict__ vT,
                                               const float* __restrict__ denom,
                                               float* __restrict__ out) {
    extern __shared__ _Float16 smem[];        // 2 x (A 16384 + B 16384) halves = 128 KiB
    float* rdI = (float*)(smem + 65536);      // 256 floats after the buffers
    const int tid = threadIdx.x;
    const int lane = tid & 63, w = tid >> 6;  // 8 waves
    const int wr = w >> 2, wcol = w & 3;      // 2 x 4 wave grid
    const int m_ = lane & 15, quad = lane >> 4;
    const int b = blockIdx.z;
    const int D0 = (blockIdx.x >> 3) * 256;   // d = x>>3
    const int I  = (blockIdx.x & 7) * 256;    // y = x&7  (same XCD for both d)
    const _Float16* Ab = W  + ((size_t)b * NN + I) * NN;
    const _Float16* Bb = vT + ((size_t)b * DD + D0) * NN;

    const int sub = lane >> 3;
    const int swc = (lane & 7) ^ sub;
    const _Float16* agl = Ab + (size_t)(w * 32 + sub) * NN + swc * 8;
    const _Float16* bgl = Bb + (size_t)(w * 32 + sub) * NN + swc * 8;

    f32x4 acc[8][4];
    #pragma unroll
    for (int i = 0; i < 8; ++i)
        #pragma unroll
        for (int j = 0; j < 4; ++j) acc[i][j] = (f32x4){0.f, 0.f, 0.f, 0.f};

#define P_STAGE(kb_) do {                                                     \
    _Float16* A_ = smem + (((kb_) & 1) << 15);                                \
    const int k0_ = (kb_) * 64;                                               \
    _Pragma("unroll")                                                         \
    for (int c = 0; c < 4; ++c) {                                             \
        async_ld16(&A_[(w * 32 + c * 8) * 64], agl + (size_t)c * 8 * NN + k0_); \
        async_ld16(&A_[16384 + (w * 32 + c * 8) * 64], bgl + (size_t)c * 8 * NN + k0_); \
    } } while (0)

#define P_COMPUTE(kb_) do {                                                   \
    const _Float16* As_ = smem + (((kb_) & 1) << 15);                         \
    const _Float16* Bs_ = As_ + 16384;                                        \
    _Pragma("unroll")                                                         \
    for (int kc = 0; kc < 2; ++kc) {                                          \
        f16x8 af[8], bf[4];                                                   \
        _Pragma("unroll")                                                     \
        for (int i = 0; i < 8; ++i) {                                         \
            const int R = wr * 128 + i * 16 + m_;                             \
            af[i] = *(const f16x8*)&As_[R * 64 + (((kc * 4 + quad) ^ (R & 7)) * 8)]; \
        }                                                                     \
        _Pragma("unroll")                                                     \
        for (int j = 0; j < 4; ++j) {                                         \
            const int Rb = wcol * 64 + j * 16 + m_;                           \
            bf[j] = *(const f16x8*)&Bs_[Rb * 64 + (((kc * 4 + quad) ^ (Rb & 7)) * 8)]; \
        }                                                                     \
        _Pragma("unroll")                                                     \
        for (int i = 0; i < 8; ++i)                                           \
            _Pragma("unroll")                                                 \
            for (int j = 0; j < 4; ++j)                                       \
                acc[i][j] = __builtin_amdgcn_mfma_f32_16x16x32_f16(af[i], bf[j], acc[i][j], 0, 0, 0); \
    } } while (0)

    P_STAGE(0); P_STAGE(1);
    for (int kb = 0; kb < NN / 64 - 1; ++kb) {
        VM_WAIT(8);                 // cur buffer's 8 loads done; next 8 in flight
        RAW_BAR();
        __builtin_amdgcn_s_setprio(1);
        P_COMPUTE(kb);
        __builtin_amdgcn_s_setprio(0);
        RAW_BAR();
        if (kb + 2 < NN / 64) P_STAGE(kb + 2);
    }
    VM_WAIT(0);
    RAW_BAR();
    __builtin_amdgcn_s_setprio(1);
    P_COMPUTE(NN / 64 - 1);
    __builtin_amdgcn_s_setprio(0);

    // Epilogue: per-row reciprocal denominators via LDS broadcast, then store.
    if (tid < 256) rdI[tid] = 1.0f / denom[b * NN + I + tid];
    LGKM_BAR();

    #pragma unroll
    for (int i = 0; i < 8; ++i) {
        const int rowb = wr * 128 + i * 16 + quad * 4;
        #pragma unroll
        for (int r = 0; r < 4; ++r) {
            const float sc = rdI[rowb + r];
            float* op = out + ((size_t)(b * NN + I + rowb + r)) * DD + D0;
            #pragma unroll
            for (int j = 0; j < 4; ++j)
                op[wcol * 64 + j * 16 + m_] = acc[i][j][r] * sc;
        }
    }
#undef P_STAGE
#undef P_COMPUTE
}

// ---------------------------------------------------------------------------
extern "C" void kernel_launch(void* const* d_in, const int* in_sizes, int n_in,
                              void* d_out, int out_size, void* d_ws, size_t ws_size,
                              hipStream_t stream) {
    const float* x = (const float*)d_in[0];
    char* ws = (char*)d_ws;
    _Float16* xhn   = (_Float16*)(ws);                        // 32 MiB normalized fp16
    _Float16* vT    = (_Float16*)(ws + (size_t)33554432);     // 32 MiB fp16 x^T
    _Float16* W     = (_Float16*)(ws + (size_t)67108864);     // 128 MiB fp16 exp-scores
    float*    denom = (float*)   (ws + (size_t)201326592);    // 128 KiB
    float*    out   = (float*)d_out;

    k_prep<<<dim3(NN / 64, BB), 256, 0, stream>>>(x, xhn, vT, denom);
    const int npairs16 = (NN / 256) * (NN / 256 + 1) / 2 * BB;   // 36*16 = 576
    k_scores<<<dim3(npairs16, 1, 1), 512, 131072, stream>>>(xhn, W, denom);
    k_pv<<<dim3(16, 1, BB), 512, 132096, stream>>>(W, vT, denom, out);
}

// Round 5
// 207.314 us; speedup vs baseline: 1.0156x; 1.0156x over previous
//
#include <hip/hip_runtime.h>
#include <hip/hip_bf16.h>
#include <cstdint>
#include <cstddef>

// Problem shape (fixed): x [B=16][N=2048][D=512] fp32
#define BB 16
#define NN 2048
#define DD 512

typedef _Float16 f16x8 __attribute__((ext_vector_type(8)));
typedef _Float16 f16x4 __attribute__((ext_vector_type(4)));
typedef float f32x4 __attribute__((ext_vector_type(4)));

// Async global->LDS, 16 B per lane. LDS dest = wave-uniform base + lane*16.
__device__ __forceinline__ void async_ld16(void* lds, const void* g) {
    __builtin_amdgcn_global_load_lds(
        (const __attribute__((address_space(1))) unsigned int*)(uintptr_t)g,
        (__attribute__((address_space(3))) unsigned int*)(uint32_t)(uintptr_t)lds,
        16, 0, 0);
}

#define VM_WAIT(n) asm volatile("s_waitcnt vmcnt(" #n ")" ::: "memory")
#define RAW_BAR()  do { asm volatile("" ::: "memory"); __builtin_amdgcn_s_barrier(); asm volatile("" ::: "memory"); } while (0)
// LDS-order-only barrier: global stores/atomics keep draining.
#define LGKM_BAR() do { asm volatile("s_waitcnt lgkmcnt(0)" ::: "memory"); \
                        __builtin_amdgcn_s_barrier();                      \
                        __builtin_amdgcn_sched_barrier(0); } while (0)
// Wait own ds_reads, then fence the scheduler (rule #18: MFMA must not hoist).
#define LGKM0_FENCE() do { asm volatile("s_waitcnt lgkmcnt(0)" ::: "memory"); \
                           __builtin_amdgcn_sched_barrier(0); } while (0)

// ---------------------------------------------------------------------------
// K1 (fused): read x ONCE. Per 64-row slab: norms, xhn (normalized fp16),
// vT (fp16 transpose), denom zero-init. grid (NN/64, BB), 256 threads.
// ---------------------------------------------------------------------------
__global__ __launch_bounds__(256) void k_prep(const float* __restrict__ x,
                                              _Float16* __restrict__ xhn,
                                              _Float16* __restrict__ vT,
                                              float* __restrict__ denom) {
    __shared__ _Float16 t[512 * 66];     // [d][j], pitch 66 halves
    const int tid = threadIdx.x, lane = tid & 63, w = tid >> 6;
    const int b = blockIdx.y, j0 = blockIdx.x * 64;
    if (tid < 64) denom[b * NN + j0 + tid] = 0.f;
    const float* xb = x + ((size_t)b * NN + j0) * DD;

    for (int rr = 0; rr < 16; ++rr) {
        const int jj = w * 16 + rr;                 // row within slab
        const float* xr = xb + (size_t)jj * DD;
        float4 a = ((const float4*)xr)[lane];       // d = 4*lane ..
        float4 c = ((const float4*)xr)[lane + 64];  // d = 256+4*lane ..
        float ss = a.x*a.x + a.y*a.y + a.z*a.z + a.w*a.w
                 + c.x*c.x + c.y*c.y + c.z*c.z + c.w*c.w;
        #pragma unroll
        for (int o = 1; o < 64; o <<= 1) ss += __shfl_xor(ss, o);
        const float rn = 1.0f / sqrtf(ss);
        // normalized fp16 row (coalesced 8B stores)
        _Float16* dst = xhn + ((size_t)b * NN + j0 + jj) * DD;
        f16x4 v0 = {(_Float16)(a.x*rn), (_Float16)(a.y*rn), (_Float16)(a.z*rn), (_Float16)(a.w*rn)};
        f16x4 v1 = {(_Float16)(c.x*rn), (_Float16)(c.y*rn), (_Float16)(c.z*rn), (_Float16)(c.w*rn)};
        *(f16x4*)(dst + 4 * lane) = v0;
        *(f16x4*)(dst + 256 + 4 * lane) = v1;
        // unnormalized fp16 into transposed LDS tile
        const int d0 = 4 * lane, d1 = 256 + 4 * lane;
        t[(d0 + 0) * 66 + jj] = (_Float16)a.x;
        t[(d0 + 1) * 66 + jj] = (_Float16)a.y;
        t[(d0 + 2) * 66 + jj] = (_Float16)a.z;
        t[(d0 + 3) * 66 + jj] = (_Float16)a.w;
        t[(d1 + 0) * 66 + jj] = (_Float16)c.x;
        t[(d1 + 1) * 66 + jj] = (_Float16)c.y;
        t[(d1 + 2) * 66 + jj] = (_Float16)c.z;
        t[(d1 + 3) * 66 + jj] = (_Float16)c.w;
    }
    LGKM_BAR();   // xhn global stores keep draining under the vT phase
    // store vT rows: 512 d x 8 chunks of 8 halves; 4B-aligned b32 LDS reads.
    #pragma unroll
    for (int it = 0; it < 16; ++it) {
        const int id = it * 256 + tid;
        const int d = id >> 3, ch = (id & 7) * 8;
        const uint32_t* tp = (const uint32_t*)&t[d * 66 + ch];
        uint4 v = {tp[0], tp[1], tp[2], tp[3]};
        *(uint4*)(vT + ((size_t)b * DD + d) * NN + j0 + ch) = v;
    }
}

// ---------------------------------------------------------------------------
// K2 (REVERTED to R3, measured 98.5-100 us): W = exp( xhn xhn^T ),
// symmetric-triangular. 128x128 block, 4 waves 64x64, BK=64, dbuf,
// counted vmcnt(8), raw barriers, setprio, LGKM-only epilogue barriers,
// XCD-aware tile-pair swizzle (136 = 8*17).
// ---------------------------------------------------------------------------
__global__ __launch_bounds__(256) void k_scores(const _Float16* __restrict__ xhn,
                                                _Float16* __restrict__ W,
                                                float* __restrict__ denom) {
    __shared__ _Float16 smem[32768];          // 2 x (As 8192 + Bs 8192); epi: 128x136
    const int tid = threadIdx.x;
    const int lane = tid & 63, wv = tid >> 6;
    const int wr = wv >> 1, wc = wv & 1;
    const int m_ = lane & 15, quad = lane >> 4;
    const int b = blockIdx.z;

    // XCD swizzle: 136 = 8 * 17 -> each XCD gets 17 consecutive pairs.
    const int swz = (blockIdx.x % 8) * 17 + blockIdx.x / 8;
    int rem = swz, ti = 0, rowlen = NN / 128;
    while (rem >= rowlen) { rem -= rowlen; ++ti; --rowlen; }
    const int tj = ti + rem;
    const int I = ti * 128, J = tj * 128;
    const bool diag = (ti == tj);

    const _Float16* Ab = xhn + ((size_t)b * NN + I) * DD;
    const _Float16* Bb = xhn + ((size_t)b * NN + J) * DD;

    f32x4 acc[4][4];
    #pragma unroll
    for (int i = 0; i < 4; ++i)
        #pragma unroll
        for (int j = 0; j < 4; ++j) acc[i][j] = (f32x4){0.f, 0.f, 0.f, 0.f};

    const int sub = lane >> 3;
    const int swc = (lane & 7) ^ sub;
    const _Float16* agl = Ab + (size_t)(wv * 32 + sub) * DD + swc * 8;
    const _Float16* bgl = Bb + (size_t)(wv * 32 + sub) * DD + swc * 8;

#define S_STAGE(kb_) do {                                                     \
    _Float16* A_ = smem + (((kb_) & 1) << 14);                                \
    const int k0_ = (kb_) * 64;                                               \
    _Pragma("unroll")                                                         \
    for (int c = 0; c < 4; ++c) {                                             \
        async_ld16(&A_[(wv * 32 + c * 8) * 64], agl + (size_t)c * 8 * DD + k0_); \
        async_ld16(&A_[8192 + (wv * 32 + c * 8) * 64], bgl + (size_t)c * 8 * DD + k0_); \
    } } while (0)

#define S_COMPUTE(kb_) do {                                                   \
    const _Float16* As_ = smem + (((kb_) & 1) << 14);                         \
    const _Float16* Bs_ = As_ + 8192;                                         \
    _Pragma("unroll")                                                         \
    for (int kc = 0; kc < 2; ++kc) {                                          \
        f16x8 af[4], bf[4];                                                   \
        _Pragma("unroll")                                                     \
        for (int t = 0; t < 4; ++t) {                                         \
            const int Ra = wr * 64 + t * 16 + m_;                             \
            const int Rb = wc * 64 + t * 16 + m_;                             \
            af[t] = *(const f16x8*)&As_[Ra * 64 + (((kc * 4 + quad) ^ (Ra & 7)) * 8)]; \
            bf[t] = *(const f16x8*)&Bs_[Rb * 64 + (((kc * 4 + quad) ^ (Rb & 7)) * 8)]; \
        }                                                                     \
        _Pragma("unroll")                                                     \
        for (int i = 0; i < 4; ++i)                                           \
            _Pragma("unroll")                                                 \
            for (int j = 0; j < 4; ++j)                                       \
                acc[i][j] = __builtin_amdgcn_mfma_f32_16x16x32_f16(af[i], bf[j], acc[i][j], 0, 0, 0); \
    } } while (0)

    S_STAGE(0); S_STAGE(1);
    for (int kb = 0; kb < DD / 64 - 1; ++kb) {
        VM_WAIT(8);                 // cur buffer's 8 loads done; next 8 stay in flight
        RAW_BAR();
        __builtin_amdgcn_s_setprio(1);
        S_COMPUTE(kb);
        __builtin_amdgcn_s_setprio(0);
        RAW_BAR();
        if (kb + 2 < DD / 64) S_STAGE(kb + 2);
    }
    VM_WAIT(0);
    RAW_BAR();
    __builtin_amdgcn_s_setprio(1);
    S_COMPUTE(DD / 64 - 1);
    __builtin_amdgcn_s_setprio(0);

    // Epilogue: exp into packed f16x4; register row/col sums.
    f16x4 wq[4][4];
    float rowpart[4][4];
    float colpart[4] = {0.f, 0.f, 0.f, 0.f};
    #pragma unroll
    for (int i = 0; i < 4; ++i)
        #pragma unroll
        for (int r = 0; r < 4; ++r) rowpart[i][r] = 0.f;

    #pragma unroll
    for (int i = 0; i < 4; ++i) {
        #pragma unroll
        for (int j = 0; j < 4; ++j) {
            #pragma unroll
            for (int r = 0; r < 4; ++r) {
                const float w = __expf(acc[i][j][r]);
                wq[i][j][r] = (_Float16)w;
                rowpart[i][r] += w;
                colpart[j] += w;
            }
        }
    }

    #pragma unroll
    for (int i = 0; i < 4; ++i) {
        #pragma unroll
        for (int r = 0; r < 4; ++r) {
            float s = rowpart[i][r];
            s += __shfl_xor(s, 1);
            s += __shfl_xor(s, 2);
            s += __shfl_xor(s, 4);
            s += __shfl_xor(s, 8);
            if (m_ == 0)
                atomicAdd(&denom[b * NN + I + wr * 64 + i * 16 + quad * 4 + r], s);
        }
    }
    if (!diag) {
        #pragma unroll
        for (int j = 0; j < 4; ++j) {
            float s = colpart[j];
            s += __shfl_xor(s, 16);
            s += __shfl_xor(s, 32);
            if (quad == 0)
                atomicAdd(&denom[b * NN + J + wc * 64 + j * 16 + m_], s);
        }
    }

    LGKM_BAR();   // LDS ordering only: atomics keep draining

    // Phase 1: WtT[col][row] (stride 136), b64 writes -> coalesced W(J,I).
    _Float16* WtT = smem;
    #pragma unroll
    for (int i = 0; i < 4; ++i) {
        const int rowb = wr * 64 + i * 16 + quad * 4;
        #pragma unroll
        for (int j = 0; j < 4; ++j) {
            const int col = wc * 64 + j * 16 + m_;
            *(f16x4*)&WtT[col * 136 + rowb] = wq[i][j];
        }
    }
    LGKM_BAR();
    {
        const int rr = tid >> 1, off = (tid & 1) * 64;
        _Float16* wg = W + ((size_t)b * NN + J + rr) * NN + I + off;
        const _Float16* wl = &WtT[rr * 136 + off];
        #pragma unroll
        for (int c = 0; c < 64; c += 8)
            *(uint4*)(wg + c) = *(const uint4*)(wl + c);
    }
    // Phase 2 (off-diag): row-major Wt -> coalesced W(I,J).
    if (!diag) {
        LGKM_BAR();   // phase-1 LDS reads done; W(J,I) stores still in flight
        _Float16* Wt = smem;
        #pragma unroll
        for (int i = 0; i < 4; ++i) {
            const int rowb = wr * 64 + i * 16 + quad * 4;
            #pragma unroll
            for (int j = 0; j < 4; ++j) {
                const int col = wc * 64 + j * 16 + m_;
                #pragma unroll
                for (int r = 0; r < 4; ++r)
                    Wt[(rowb + r) * 136 + col] = wq[i][j][r];
            }
        }
        LGKM_BAR();
        const int rr = tid >> 1, off = (tid & 1) * 64;
        _Float16* wg = W + ((size_t)b * NN + I + rr) * NN + J + off;
        const _Float16* wl = &Wt[rr * 136 + off];
        #pragma unroll
        for (int c = 0; c < 64; c += 8)
            *(uint4*)(wg + c) = *(const uint4*)(wl + c);
    }
#undef S_STAGE
#undef S_COMPUTE
}

// ---------------------------------------------------------------------------
// K3: O = (W @ V) * (1/denom_i), fp32 out.
// NEW: 4-phase-per-K-tile schedule (T3+T4+T5 proper): each K-tile's 64
// MFMAs/wave split into 4 C-quadrant phases of 16, each phase =
// {clustered ds_reads -> barrier -> lgkmcnt(0)+sched_barrier -> setprio(1)
//  16 MFMA setprio(0) -> barrier}. Stage burst for tile t+2 at P3 (issue-to-
// consume ~5 phases ~800cy). vmcnt(8) once per tile; vmcnt(0) only last tile.
// 256x256 tile, 8 waves 2Mx4N, BK=64, 128 KiB dbuf, grid (16,1,B).
// ---------------------------------------------------------------------------
__global__ __launch_bounds__(512, 2) void k_pv(const _Float16* __restrict__ W,
                                               const _Float16* __restrict__ vT,
                                               const float* __restrict__ denom,
                                               float* __restrict__ out) {
    extern __shared__ _Float16 smem[];        // 2 x (A 16384 + B 16384) halves = 128 KiB
    float* rdI = (float*)(smem + 65536);      // 256 floats after the buffers
    const int tid = threadIdx.x;
    const int lane = tid & 63, w = tid >> 6;  // 8 waves
    const int wr = w >> 2, wcol = w & 3;      // 2 x 4 wave grid
    const int m_ = lane & 15, quad = lane >> 4;
    const int b = blockIdx.z;
    const int D0 = (blockIdx.x >> 3) * 256;   // d = x>>3
    const int I  = (blockIdx.x & 7) * 256;    // y = x&7  (same XCD for both d)
    const _Float16* Ab = W  + ((size_t)b * NN + I) * NN;
    const _Float16* Bb = vT + ((size_t)b * DD + D0) * NN;

    const int sub = lane >> 3;
    const int swc = (lane & 7) ^ sub;
    const _Float16* agl = Ab + (size_t)(w * 32 + sub) * NN + swc * 8;
    const _Float16* bgl = Bb + (size_t)(w * 32 + sub) * NN + swc * 8;

    f32x4 acc[8][4];
    #pragma unroll
    for (int i = 0; i < 8; ++i)
        #pragma unroll
        for (int j = 0; j < 4; ++j) acc[i][j] = (f32x4){0.f, 0.f, 0.f, 0.f};

    f16x8 afq[4][2];   // current i-quadrant A frags (kc 0,1)
    f16x8 bfq[4][2];   // all four j B frags (kc 0,1)

#define P_STAGE(kb_) do {                                                     \
    _Float16* A_ = smem + (((kb_) & 1) << 15);                                \
    const int k0_ = (kb_) * 64;                                               \
    _Pragma("unroll")                                                         \
    for (int c = 0; c < 4; ++c) {                                             \
        async_ld16(&A_[(w * 32 + c * 8) * 64], agl + (size_t)c * 8 * NN + k0_); \
        async_ld16(&A_[16384 + (w * 32 + c * 8) * 64], bgl + (size_t)c * 8 * NN + k0_); \
    } } while (0)

#define LD_A(t_, ih_) do {                                                    \
    const int R = wr * 128 + ((ih_) * 4 + (t_)) * 16 + m_;                    \
    afq[t_][0] = *(const f16x8*)&As_[R * 64 + ((quad ^ (R & 7)) * 8)];        \
    afq[t_][1] = *(const f16x8*)&As_[R * 64 + (((4 + quad) ^ (R & 7)) * 8)];  \
    } while (0)

#define LD_B(j_) do {                                                         \
    const int Rb = wcol * 64 + (j_) * 16 + m_;                                \
    bfq[j_][0] = *(const f16x8*)&Bs_[Rb * 64 + ((quad ^ (Rb & 7)) * 8)];      \
    bfq[j_][1] = *(const f16x8*)&Bs_[Rb * 64 + (((4 + quad) ^ (Rb & 7)) * 8)];\
    } while (0)

#define MFMA_Q(ih_, jh_) do {                                                 \
    __builtin_amdgcn_s_setprio(1);                                            \
    _Pragma("unroll")                                                         \
    for (int t = 0; t < 4; ++t)                                               \
        _Pragma("unroll")                                                     \
        for (int j = 0; j < 2; ++j) {                                         \
            acc[(ih_)*4+t][(jh_)*2+j] = __builtin_amdgcn_mfma_f32_16x16x32_f16( \
                afq[t][0], bfq[(jh_)*2+j][0], acc[(ih_)*4+t][(jh_)*2+j], 0, 0, 0); \
            acc[(ih_)*4+t][(jh_)*2+j] = __builtin_amdgcn_mfma_f32_16x16x32_f16( \
                afq[t][1], bfq[(jh_)*2+j][1], acc[(ih_)*4+t][(jh_)*2+j], 0, 0, 0); \
        }                                                                     \
    __builtin_amdgcn_s_setprio(0);                                            \
    } while (0)

    P_STAGE(0); P_STAGE(1);
    const int NT = NN / 64;
    for (int tc = 0; tc < NT; ++tc) {
        const _Float16* As_ = smem + ((tc & 1) << 15);
        const _Float16* Bs_ = As_ + 16384;
        if (tc == NT - 1) { VM_WAIT(0); } else { VM_WAIT(8); }
        RAW_BAR();
        // ---- P0: quadrant (0,0). reads: af[0..3] (8) + bf[0..1] (4)
        #pragma unroll
        for (int t = 0; t < 4; ++t) LD_A(t, 0);
        LD_B(0); LD_B(1);
        RAW_BAR();
        LGKM0_FENCE();
        MFMA_Q(0, 0);
        RAW_BAR();
        // ---- P1: quadrant (0,1). reads: bf[2..3] (4)
        LD_B(2); LD_B(3);
        RAW_BAR();
        LGKM0_FENCE();
        MFMA_Q(0, 1);
        RAW_BAR();
        // ---- P2: quadrant (1,0). reads: af[4..7] (8)
        #pragma unroll
        for (int t = 0; t < 4; ++t) LD_A(t, 1);
        RAW_BAR();
        LGKM0_FENCE();
        MFMA_Q(1, 0);
        RAW_BAR();
        // ---- P3: quadrant (1,1). no reads; stage tile tc+2 (8 gloads)
        if (tc + 2 < NT) P_STAGE(tc + 2);
        RAW_BAR();
        MFMA_Q(1, 1);
        RAW_BAR();
    }

    // Epilogue: per-row reciprocal denominators via LDS broadcast, then store.
    if (tid < 256) rdI[tid] = 1.0f / denom[b * NN + I + tid];
    LGKM_BAR();

    #pragma unroll
    for (int i = 0; i < 8; ++i) {
        const int rowb = wr * 128 + i * 16 + quad * 4;
        #pragma unroll
        for (int r = 0; r < 4; ++r) {
            const float sc = rdI[rowb + r];
            float* op = out + ((size_t)(b * NN + I + rowb + r)) * DD + D0;
            #pragma unroll
            for (int j = 0; j < 4; ++j)
                op[wcol * 64 + j * 16 + m_] = acc[i][j][r] * sc;
        }
    }
#undef P_STAGE
#undef LD_A
#undef LD_B
#undef MFMA_Q
}

// ---------------------------------------------------------------------------
extern "C" void kernel_launch(void* const* d_in, const int* in_sizes, int n_in,
                              void* d_out, int out_size, void* d_ws, size_t ws_size,
                              hipStream_t stream) {
    const float* x = (const float*)d_in[0];
    char* ws = (char*)d_ws;
    _Float16* xhn   = (_Float16*)(ws);                        // 32 MiB normalized fp16
    _Float16* vT    = (_Float16*)(ws + (size_t)33554432);     // 32 MiB fp16 x^T
    _Float16* W     = (_Float16*)(ws + (size_t)67108864);     // 128 MiB fp16 exp-scores
    float*    denom = (float*)   (ws + (size_t)201326592);    // 128 KiB
    float*    out   = (float*)d_out;

    k_prep<<<dim3(NN / 64, BB), 256, 0, stream>>>(x, xhn, vT, denom);
    const int npairs = (NN / 128) * (NN / 128 + 1) / 2;   // 136
    k_scores<<<dim3(npairs, 1, BB), 256, 0, stream>>>(xhn, W, denom);
    // 128 KiB LDS buffers + 1 KiB rdI, dynamic (exceeds 64 KiB static limit)
    k_pv<<<dim3(16, 1, BB), 512, 132096, stream>>>(W, vT, denom, out);
}

// Round 6
// 185.712 us; speedup vs baseline: 1.1337x; 1.1163x over previous
//
#include <hip/hip_runtime.h>
#include <hip/hip_bf16.h>
#include <cstdint>
#include <cstddef>

// Problem shape (fixed): x [B=16][N=2048][D=512] fp32
#define BB 16
#define NN 2048
#define DD 512

typedef _Float16 f16x8 __attribute__((ext_vector_type(8)));
typedef _Float16 f16x4 __attribute__((ext_vector_type(4)));
typedef float f32x4 __attribute__((ext_vector_type(4)));

// Async global->LDS, 16 B per lane. LDS dest = wave-uniform base + lane*16.
__device__ __forceinline__ void async_ld16(void* lds, const void* g) {
    __builtin_amdgcn_global_load_lds(
        (const __attribute__((address_space(1))) unsigned int*)(uintptr_t)g,
        (__attribute__((address_space(3))) unsigned int*)(uint32_t)(uintptr_t)lds,
        16, 0, 0);
}

#define VM_WAIT(n) asm volatile("s_waitcnt vmcnt(" #n ")" ::: "memory")
#define RAW_BAR()  do { asm volatile("" ::: "memory"); __builtin_amdgcn_s_barrier(); asm volatile("" ::: "memory"); } while (0)
// LDS-order-only barrier: global stores/atomics keep draining.
#define LGKM_BAR() do { asm volatile("s_waitcnt lgkmcnt(0)" ::: "memory"); \
                        __builtin_amdgcn_s_barrier();                      \
                        __builtin_amdgcn_sched_barrier(0); } while (0)
// Wait own ds_reads, then fence the scheduler (rule #18: MFMA must not hoist).
#define LGKM0_FENCE() do { asm volatile("s_waitcnt lgkmcnt(0)" ::: "memory"); \
                           __builtin_amdgcn_sched_barrier(0); } while (0)

// ---------------------------------------------------------------------------
// K1 (fused): read x ONCE. Per 64-row slab: norms, xhn (normalized fp16),
// vT (fp16 transpose), denom zero-init. grid (NN/64, BB), 256 threads.
// ---------------------------------------------------------------------------
__global__ __launch_bounds__(256) void k_prep(const float* __restrict__ x,
                                              _Float16* __restrict__ xhn,
                                              _Float16* __restrict__ vT,
                                              float* __restrict__ denom) {
    __shared__ _Float16 t[512 * 66];     // [d][j], pitch 66 halves
    const int tid = threadIdx.x, lane = tid & 63, w = tid >> 6;
    const int b = blockIdx.y, j0 = blockIdx.x * 64;
    if (tid < 64) denom[b * NN + j0 + tid] = 0.f;
    const float* xb = x + ((size_t)b * NN + j0) * DD;

    for (int rr = 0; rr < 16; ++rr) {
        const int jj = w * 16 + rr;                 // row within slab
        const float* xr = xb + (size_t)jj * DD;
        float4 a = ((const float4*)xr)[lane];       // d = 4*lane ..
        float4 c = ((const float4*)xr)[lane + 64];  // d = 256+4*lane ..
        float ss = a.x*a.x + a.y*a.y + a.z*a.z + a.w*a.w
                 + c.x*c.x + c.y*c.y + c.z*c.z + c.w*c.w;
        #pragma unroll
        for (int o = 1; o < 64; o <<= 1) ss += __shfl_xor(ss, o);
        const float rn = 1.0f / sqrtf(ss);
        // normalized fp16 row (coalesced 8B stores)
        _Float16* dst = xhn + ((size_t)b * NN + j0 + jj) * DD;
        f16x4 v0 = {(_Float16)(a.x*rn), (_Float16)(a.y*rn), (_Float16)(a.z*rn), (_Float16)(a.w*rn)};
        f16x4 v1 = {(_Float16)(c.x*rn), (_Float16)(c.y*rn), (_Float16)(c.z*rn), (_Float16)(c.w*rn)};
        *(f16x4*)(dst + 4 * lane) = v0;
        *(f16x4*)(dst + 256 + 4 * lane) = v1;
        // unnormalized fp16 into transposed LDS tile
        const int d0 = 4 * lane, d1 = 256 + 4 * lane;
        t[(d0 + 0) * 66 + jj] = (_Float16)a.x;
        t[(d0 + 1) * 66 + jj] = (_Float16)a.y;
        t[(d0 + 2) * 66 + jj] = (_Float16)a.z;
        t[(d0 + 3) * 66 + jj] = (_Float16)a.w;
        t[(d1 + 0) * 66 + jj] = (_Float16)c.x;
        t[(d1 + 1) * 66 + jj] = (_Float16)c.y;
        t[(d1 + 2) * 66 + jj] = (_Float16)c.z;
        t[(d1 + 3) * 66 + jj] = (_Float16)c.w;
    }
    LGKM_BAR();   // xhn global stores keep draining under the vT phase
    // store vT rows: 512 d x 8 chunks of 8 halves; 4B-aligned b32 LDS reads.
    #pragma unroll
    for (int it = 0; it < 16; ++it) {
        const int id = it * 256 + tid;
        const int d = id >> 3, ch = (id & 7) * 8;
        const uint32_t* tp = (const uint32_t*)&t[d * 66 + ch];
        uint4 v = {tp[0], tp[1], tp[2], tp[3]};
        *(uint4*)(vT + ((size_t)b * DD + d) * NN + j0 + ch) = v;
    }
}

// ---------------------------------------------------------------------------
// K2: W = exp( xhn xhn^T ), symmetric-triangular. 128x128 block, 4 waves,
// BK=64, dbuf, counted vmcnt(8), raw barriers, setprio, LGKM-only epilogue
// barriers, XCD-aware tile-pair swizzle (136 = 8*17).
// NEW this round: W stores lane-coalesced (16 consecutive lanes = one
// contiguous 256 B row segment, instead of 8 sequential 16B chunks per
// thread at 4 KB lane stride -> ~4x fewer L2 requests on 284 MB of stores).
// ---------------------------------------------------------------------------
__global__ __launch_bounds__(256) void k_scores(const _Float16* __restrict__ xhn,
                                                _Float16* __restrict__ W,
                                                float* __restrict__ denom) {
    __shared__ _Float16 smem[32768];          // 2 x (As 8192 + Bs 8192); epi: 128x136
    const int tid = threadIdx.x;
    const int lane = tid & 63, wv = tid >> 6;
    const int wr = wv >> 1, wc = wv & 1;
    const int m_ = lane & 15, quad = lane >> 4;
    const int b = blockIdx.z;

    // XCD swizzle: 136 = 8 * 17 -> each XCD gets 17 consecutive pairs.
    const int swz = (blockIdx.x % 8) * 17 + blockIdx.x / 8;
    int rem = swz, ti = 0, rowlen = NN / 128;
    while (rem >= rowlen) { rem -= rowlen; ++ti; --rowlen; }
    const int tj = ti + rem;
    const int I = ti * 128, J = tj * 128;
    const bool diag = (ti == tj);

    const _Float16* Ab = xhn + ((size_t)b * NN + I) * DD;
    const _Float16* Bb = xhn + ((size_t)b * NN + J) * DD;

    f32x4 acc[4][4];
    #pragma unroll
    for (int i = 0; i < 4; ++i)
        #pragma unroll
        for (int j = 0; j < 4; ++j) acc[i][j] = (f32x4){0.f, 0.f, 0.f, 0.f};

    const int sub = lane >> 3;
    const int swc = (lane & 7) ^ sub;
    const _Float16* agl = Ab + (size_t)(wv * 32 + sub) * DD + swc * 8;
    const _Float16* bgl = Bb + (size_t)(wv * 32 + sub) * DD + swc * 8;

#define S_STAGE(kb_) do {                                                     \
    _Float16* A_ = smem + (((kb_) & 1) << 14);                                \
    const int k0_ = (kb_) * 64;                                               \
    _Pragma("unroll")                                                         \
    for (int c = 0; c < 4; ++c) {                                             \
        async_ld16(&A_[(wv * 32 + c * 8) * 64], agl + (size_t)c * 8 * DD + k0_); \
        async_ld16(&A_[8192 + (wv * 32 + c * 8) * 64], bgl + (size_t)c * 8 * DD + k0_); \
    } } while (0)

#define S_COMPUTE(kb_) do {                                                   \
    const _Float16* As_ = smem + (((kb_) & 1) << 14);                         \
    const _Float16* Bs_ = As_ + 8192;                                         \
    _Pragma("unroll")                                                         \
    for (int kc = 0; kc < 2; ++kc) {                                          \
        f16x8 af[4], bf[4];                                                   \
        _Pragma("unroll")                                                     \
        for (int t = 0; t < 4; ++t) {                                         \
            const int Ra = wr * 64 + t * 16 + m_;                             \
            const int Rb = wc * 64 + t * 16 + m_;                             \
            af[t] = *(const f16x8*)&As_[Ra * 64 + (((kc * 4 + quad) ^ (Ra & 7)) * 8)]; \
            bf[t] = *(const f16x8*)&Bs_[Rb * 64 + (((kc * 4 + quad) ^ (Rb & 7)) * 8)]; \
        }                                                                     \
        _Pragma("unroll")                                                     \
        for (int i = 0; i < 4; ++i)                                           \
            _Pragma("unroll")                                                 \
            for (int j = 0; j < 4; ++j)                                       \
                acc[i][j] = __builtin_amdgcn_mfma_f32_16x16x32_f16(af[i], bf[j], acc[i][j], 0, 0, 0); \
    } } while (0)

    S_STAGE(0); S_STAGE(1);
    for (int kb = 0; kb < DD / 64 - 1; ++kb) {
        VM_WAIT(8);                 // cur buffer's 8 loads done; next 8 stay in flight
        RAW_BAR();
        __builtin_amdgcn_s_setprio(1);
        S_COMPUTE(kb);
        __builtin_amdgcn_s_setprio(0);
        RAW_BAR();
        if (kb + 2 < DD / 64) S_STAGE(kb + 2);
    }
    VM_WAIT(0);
    RAW_BAR();
    __builtin_amdgcn_s_setprio(1);
    S_COMPUTE(DD / 64 - 1);
    __builtin_amdgcn_s_setprio(0);

    // Epilogue: exp into packed f16x4; register row/col sums.
    f16x4 wq[4][4];
    float rowpart[4][4];
    float colpart[4] = {0.f, 0.f, 0.f, 0.f};
    #pragma unroll
    for (int i = 0; i < 4; ++i)
        #pragma unroll
        for (int r = 0; r < 4; ++r) rowpart[i][r] = 0.f;

    #pragma unroll
    for (int i = 0; i < 4; ++i) {
        #pragma unroll
        for (int j = 0; j < 4; ++j) {
            #pragma unroll
            for (int r = 0; r < 4; ++r) {
                const float w = __expf(acc[i][j][r]);
                wq[i][j][r] = (_Float16)w;
                rowpart[i][r] += w;
                colpart[j] += w;
            }
        }
    }

    #pragma unroll
    for (int i = 0; i < 4; ++i) {
        #pragma unroll
        for (int r = 0; r < 4; ++r) {
            float s = rowpart[i][r];
            s += __shfl_xor(s, 1);
            s += __shfl_xor(s, 2);
            s += __shfl_xor(s, 4);
            s += __shfl_xor(s, 8);
            if (m_ == 0)
                atomicAdd(&denom[b * NN + I + wr * 64 + i * 16 + quad * 4 + r], s);
        }
    }
    if (!diag) {
        #pragma unroll
        for (int j = 0; j < 4; ++j) {
            float s = colpart[j];
            s += __shfl_xor(s, 16);
            s += __shfl_xor(s, 32);
            if (quad == 0)
                atomicAdd(&denom[b * NN + J + wc * 64 + j * 16 + m_], s);
        }
    }

    LGKM_BAR();   // LDS ordering only: atomics keep draining

    // Phase 1: WtT[col][row] (stride 136), b64 writes -> coalesced W(J,I).
    _Float16* WtT = smem;
    #pragma unroll
    for (int i = 0; i < 4; ++i) {
        const int rowb = wr * 64 + i * 16 + quad * 4;
        #pragma unroll
        for (int j = 0; j < 4; ++j) {
            const int col = wc * 64 + j * 16 + m_;
            *(f16x4*)&WtT[col * 136 + rowb] = wq[i][j];
        }
    }
    LGKM_BAR();
    // lane-coalesced store: id -> row = id>>4, 16B chunk = (id&15);
    // 16 consecutive lanes cover one contiguous 256 B row segment.
    #pragma unroll
    for (int it2 = 0; it2 < 8; ++it2) {
        const int id = it2 * 256 + tid;
        const int rr = id >> 4, off = (id & 15) * 8;
        *(uint4*)(W + ((size_t)b * NN + J + rr) * NN + I + off) =
            *(const uint4*)&WtT[rr * 136 + off];
    }
    // Phase 2 (off-diag): row-major Wt -> coalesced W(I,J).
    if (!diag) {
        LGKM_BAR();   // phase-1 LDS reads done; W(J,I) stores still in flight
        _Float16* Wt = smem;
        #pragma unroll
        for (int i = 0; i < 4; ++i) {
            const int rowb = wr * 64 + i * 16 + quad * 4;
            #pragma unroll
            for (int j = 0; j < 4; ++j) {
                const int col = wc * 64 + j * 16 + m_;
                #pragma unroll
                for (int r = 0; r < 4; ++r)
                    Wt[(rowb + r) * 136 + col] = wq[i][j][r];
            }
        }
        LGKM_BAR();
        #pragma unroll
        for (int it2 = 0; it2 < 8; ++it2) {
            const int id = it2 * 256 + tid;
            const int rr = id >> 4, off = (id & 15) * 8;
            *(uint4*)(W + ((size_t)b * NN + I + rr) * NN + J + off) =
                *(const uint4*)&Wt[rr * 136 + off];
        }
    }
#undef S_STAGE
#undef S_COMPUTE
}

// ---------------------------------------------------------------------------
// K3: O = (W @ V) * (1/denom_i), fp32 out.
// 256x256 tile, 8 waves 2Mx4N, BK=64, 128 KiB dbuf, 4-phase counted-vmcnt.
// NEW: XCD batch-pinning. Grid flat 256 = 1 block/CU, all co-resident.
// blockIdx.x = slot*8 + xcd (dispatch round-robins xcd = bx%8):
//   xcd = b%8  -> each XCD holds 2 batches; vT(batch) = 2 MiB <= 4 MiB L2
//   -> vT fetched from HBM once (was 8x refetch across XCDs);
//   d-pair blocks of same (b,I) adjacent slots -> W panel L2-shared.
// ---------------------------------------------------------------------------
__global__ __launch_bounds__(512, 2) void k_pv(const _Float16* __restrict__ W,
                                               const _Float16* __restrict__ vT,
                                               const float* __restrict__ denom,
                                               float* __restrict__ out) {
    extern __shared__ _Float16 smem[];        // 2 x (A 16384 + B 16384) halves = 128 KiB
    float* rdI = (float*)(smem + 65536);      // 256 floats after the buffers
    const int tid = threadIdx.x;
    const int lane = tid & 63, w = tid >> 6;  // 8 waves
    const int wr = w >> 2, wcol = w & 3;      // 2 x 4 wave grid
    const int m_ = lane & 15, quad = lane >> 4;

    // XCD pinning: bx -> (xcd, slot); b = (slot>>4)*8 + xcd; I,d from slot.
    const int bx = blockIdx.x;
    const int xcd = bx & 7, slot = bx >> 3;
    const int b  = (slot >> 4) * 8 + xcd;
    const int I  = ((slot >> 1) & 7) * 256;
    const int D0 = (slot & 1) * 256;

    const _Float16* Ab = W  + ((size_t)b * NN + I) * NN;
    const _Float16* Bb = vT + ((size_t)b * DD + D0) * NN;

    const int sub = lane >> 3;
    const int swc = (lane & 7) ^ sub;
    const _Float16* agl = Ab + (size_t)(w * 32 + sub) * NN + swc * 8;
    const _Float16* bgl = Bb + (size_t)(w * 32 + sub) * NN + swc * 8;

    f32x4 acc[8][4];
    #pragma unroll
    for (int i = 0; i < 8; ++i)
        #pragma unroll
        for (int j = 0; j < 4; ++j) acc[i][j] = (f32x4){0.f, 0.f, 0.f, 0.f};

    f16x8 afq[4][2];   // current i-quadrant A frags (kc 0,1)
    f16x8 bfq[4][2];   // all four j B frags (kc 0,1)

#define P_STAGE(kb_) do {                                                     \
    _Float16* A_ = smem + (((kb_) & 1) << 15);                                \
    const int k0_ = (kb_) * 64;                                               \
    _Pragma("unroll")                                                         \
    for (int c = 0; c < 4; ++c) {                                             \
        async_ld16(&A_[(w * 32 + c * 8) * 64], agl + (size_t)c * 8 * NN + k0_); \
        async_ld16(&A_[16384 + (w * 32 + c * 8) * 64], bgl + (size_t)c * 8 * NN + k0_); \
    } } while (0)

#define LD_A(t_, ih_) do {                                                    \
    const int R = wr * 128 + ((ih_) * 4 + (t_)) * 16 + m_;                    \
    afq[t_][0] = *(const f16x8*)&As_[R * 64 + ((quad ^ (R & 7)) * 8)];        \
    afq[t_][1] = *(const f16x8*)&As_[R * 64 + (((4 + quad) ^ (R & 7)) * 8)];  \
    } while (0)

#define LD_B(j_) do {                                                         \
    const int Rb = wcol * 64 + (j_) * 16 + m_;                                \
    bfq[j_][0] = *(const f16x8*)&Bs_[Rb * 64 + ((quad ^ (Rb & 7)) * 8)];      \
    bfq[j_][1] = *(const f16x8*)&Bs_[Rb * 64 + (((4 + quad) ^ (Rb & 7)) * 8)];\
    } while (0)

#define MFMA_Q(ih_, jh_) do {                                                 \
    __builtin_amdgcn_s_setprio(1);                                            \
    _Pragma("unroll")                                                         \
    for (int t = 0; t < 4; ++t)                                               \
        _Pragma("unroll")                                                     \
        for (int j = 0; j < 2; ++j) {                                         \
            acc[(ih_)*4+t][(jh_)*2+j] = __builtin_amdgcn_mfma_f32_16x16x32_f16( \
                afq[t][0], bfq[(jh_)*2+j][0], acc[(ih_)*4+t][(jh_)*2+j], 0, 0, 0); \
            acc[(ih_)*4+t][(jh_)*2+j] = __builtin_amdgcn_mfma_f32_16x16x32_f16( \
                afq[t][1], bfq[(jh_)*2+j][1], acc[(ih_)*4+t][(jh_)*2+j], 0, 0, 0); \
        }                                                                     \
    __builtin_amdgcn_s_setprio(0);                                            \
    } while (0)

    P_STAGE(0); P_STAGE(1);
    const int NT = NN / 64;
    for (int tc = 0; tc < NT; ++tc) {
        const _Float16* As_ = smem + ((tc & 1) << 15);
        const _Float16* Bs_ = As_ + 16384;
        if (tc == NT - 1) { VM_WAIT(0); } else { VM_WAIT(8); }
        RAW_BAR();
        // ---- P0: quadrant (0,0). reads: af[0..3] (8) + bf[0..1] (4)
        #pragma unroll
        for (int t = 0; t < 4; ++t) LD_A(t, 0);
        LD_B(0); LD_B(1);
        RAW_BAR();
        LGKM0_FENCE();
        MFMA_Q(0, 0);
        RAW_BAR();
        // ---- P1: quadrant (0,1). reads: bf[2..3] (4)
        LD_B(2); LD_B(3);
        RAW_BAR();
        LGKM0_FENCE();
        MFMA_Q(0, 1);
        RAW_BAR();
        // ---- P2: quadrant (1,0). reads: af[4..7] (8)
        #pragma unroll
        for (int t = 0; t < 4; ++t) LD_A(t, 1);
        RAW_BAR();
        LGKM0_FENCE();
        MFMA_Q(1, 0);
        RAW_BAR();
        // ---- P3: quadrant (1,1). no reads; stage tile tc+2 (8 gloads)
        if (tc + 2 < NT) P_STAGE(tc + 2);
        RAW_BAR();
        MFMA_Q(1, 1);
        RAW_BAR();
    }

    // Epilogue: per-row reciprocal denominators via LDS broadcast, then store.
    if (tid < 256) rdI[tid] = 1.0f / denom[b * NN + I + tid];
    LGKM_BAR();

    #pragma unroll
    for (int i = 0; i < 8; ++i) {
        const int rowb = wr * 128 + i * 16 + quad * 4;
        #pragma unroll
        for (int r = 0; r < 4; ++r) {
            const float sc = rdI[rowb + r];
            float* op = out + ((size_t)(b * NN + I + rowb + r)) * DD + D0;
            #pragma unroll
            for (int j = 0; j < 4; ++j)
                op[wcol * 64 + j * 16 + m_] = acc[i][j][r] * sc;
        }
    }
#undef P_STAGE
#undef LD_A
#undef LD_B
#undef MFMA_Q
}

// ---------------------------------------------------------------------------
extern "C" void kernel_launch(void* const* d_in, const int* in_sizes, int n_in,
                              void* d_out, int out_size, void* d_ws, size_t ws_size,
                              hipStream_t stream) {
    const float* x = (const float*)d_in[0];
    char* ws = (char*)d_ws;
    _Float16* xhn   = (_Float16*)(ws);                        // 32 MiB normalized fp16
    _Float16* vT    = (_Float16*)(ws + (size_t)33554432);     // 32 MiB fp16 x^T
    _Float16* W     = (_Float16*)(ws + (size_t)67108864);     // 128 MiB fp16 exp-scores
    float*    denom = (float*)   (ws + (size_t)201326592);    // 128 KiB
    float*    out   = (float*)d_out;

    k_prep<<<dim3(NN / 64, BB), 256, 0, stream>>>(x, xhn, vT, denom);
    const int npairs = (NN / 128) * (NN / 128 + 1) / 2;   // 136
    k_scores<<<dim3(npairs, 1, BB), 256, 0, stream>>>(xhn, W, denom);
    // flat 256-block grid, XCD batch-pinned; 128 KiB dbuf + 1 KiB rdI dynamic
    k_pv<<<dim3(256, 1, 1), 512, 132096, stream>>>(W, vT, denom, out);
}

// Round 7
// 178.634 us; speedup vs baseline: 1.1786x; 1.0396x over previous
//
#include <hip/hip_runtime.h>
#include <hip/hip_bf16.h>
#include <cstdint>
#include <cstddef>

// Problem shape (fixed): x [B=16][N=2048][D=512] fp32
#define BB 16
#define NN 2048
#define DD 512

typedef _Float16 f16x8 __attribute__((ext_vector_type(8)));
typedef _Float16 f16x4 __attribute__((ext_vector_type(4)));
typedef float f32x4 __attribute__((ext_vector_type(4)));

// Async global->LDS, 16 B per lane. LDS dest = wave-uniform base + lane*16.
__device__ __forceinline__ void async_ld16(void* lds, const void* g) {
    __builtin_amdgcn_global_load_lds(
        (const __attribute__((address_space(1))) unsigned int*)(uintptr_t)g,
        (__attribute__((address_space(3))) unsigned int*)(uint32_t)(uintptr_t)lds,
        16, 0, 0);
}

#define VM_WAIT(n) asm volatile("s_waitcnt vmcnt(" #n ")" ::: "memory")
#define RAW_BAR()  do { asm volatile("" ::: "memory"); __builtin_amdgcn_s_barrier(); asm volatile("" ::: "memory"); } while (0)
// LDS-order-only barrier: global stores/atomics keep draining.
#define LGKM_BAR() do { asm volatile("s_waitcnt lgkmcnt(0)" ::: "memory"); \
                        __builtin_amdgcn_s_barrier();                      \
                        __builtin_amdgcn_sched_barrier(0); } while (0)
// Wait own ds_reads, then fence the scheduler (rule #18: MFMA must not hoist).
#define LGKM0_FENCE() do { asm volatile("s_waitcnt lgkmcnt(0)" ::: "memory"); \
                           __builtin_amdgcn_sched_barrier(0); } while (0)

// ---------------------------------------------------------------------------
// K1 (fused): read x ONCE. Per 64-row slab: norms, xhn (normalized fp16),
// vT (fp16 transpose), denom zero-init. grid (NN/64, BB), 256 threads.
// ---------------------------------------------------------------------------
__global__ __launch_bounds__(256) void k_prep(const float* __restrict__ x,
                                              _Float16* __restrict__ xhn,
                                              _Float16* __restrict__ vT,
                                              float* __restrict__ denom) {
    __shared__ _Float16 t[512 * 66];     // [d][j], pitch 66 halves
    const int tid = threadIdx.x, lane = tid & 63, w = tid >> 6;
    const int b = blockIdx.y, j0 = blockIdx.x * 64;
    if (tid < 64) denom[b * NN + j0 + tid] = 0.f;
    const float* xb = x + ((size_t)b * NN + j0) * DD;

    for (int rr = 0; rr < 16; ++rr) {
        const int jj = w * 16 + rr;                 // row within slab
        const float* xr = xb + (size_t)jj * DD;
        float4 a = ((const float4*)xr)[lane];       // d = 4*lane ..
        float4 c = ((const float4*)xr)[lane + 64];  // d = 256+4*lane ..
        float ss = a.x*a.x + a.y*a.y + a.z*a.z + a.w*a.w
                 + c.x*c.x + c.y*c.y + c.z*c.z + c.w*c.w;
        #pragma unroll
        for (int o = 1; o < 64; o <<= 1) ss += __shfl_xor(ss, o);
        const float rn = 1.0f / sqrtf(ss);
        // normalized fp16 row (coalesced 8B stores)
        _Float16* dst = xhn + ((size_t)b * NN + j0 + jj) * DD;
        f16x4 v0 = {(_Float16)(a.x*rn), (_Float16)(a.y*rn), (_Float16)(a.z*rn), (_Float16)(a.w*rn)};
        f16x4 v1 = {(_Float16)(c.x*rn), (_Float16)(c.y*rn), (_Float16)(c.z*rn), (_Float16)(c.w*rn)};
        *(f16x4*)(dst + 4 * lane) = v0;
        *(f16x4*)(dst + 256 + 4 * lane) = v1;
        // unnormalized fp16 into transposed LDS tile
        const int d0 = 4 * lane, d1 = 256 + 4 * lane;
        t[(d0 + 0) * 66 + jj] = (_Float16)a.x;
        t[(d0 + 1) * 66 + jj] = (_Float16)a.y;
        t[(d0 + 2) * 66 + jj] = (_Float16)a.z;
        t[(d0 + 3) * 66 + jj] = (_Float16)a.w;
        t[(d1 + 0) * 66 + jj] = (_Float16)c.x;
        t[(d1 + 1) * 66 + jj] = (_Float16)c.y;
        t[(d1 + 2) * 66 + jj] = (_Float16)c.z;
        t[(d1 + 3) * 66 + jj] = (_Float16)c.w;
    }
    LGKM_BAR();   // xhn global stores keep draining under the vT phase
    // store vT rows: 512 d x 8 chunks of 8 halves; 4B-aligned b32 LDS reads.
    #pragma unroll
    for (int it = 0; it < 16; ++it) {
        const int id = it * 256 + tid;
        const int d = id >> 3, ch = (id & 7) * 8;
        const uint32_t* tp = (const uint32_t*)&t[d * 66 + ch];
        uint4 v = {tp[0], tp[1], tp[2], tp[3]};
        *(uint4*)(vT + ((size_t)b * DD + d) * NN + j0 + ch) = v;
    }
}

// ---------------------------------------------------------------------------
// K2: W = exp( xhn xhn^T ), symmetric-triangular. 128x128 block, 4 waves.
// NEW this round: SINGLE-buffered BK=64 (m97-classic: stage -> vmcnt(0) ->
// barrier -> MFMA -> barrier). LDS 34 KiB -> 4 blocks/CU (was 64 KiB / 2):
// cross-block TLP hides the per-step drain + epilogue serialization (m114),
// and the dispatch tail shrinks (2.1 rounds vs 4.25).
// Epilogue unchanged from R6 (register sums -> atomics; LDS transposes;
// lane-coalesced 256B-segment stores; LGKM-only barriers).
// ---------------------------------------------------------------------------
__global__ __launch_bounds__(256, 4) void k_scores(const _Float16* __restrict__ xhn,
                                                   _Float16* __restrict__ W,
                                                   float* __restrict__ denom) {
    __shared__ _Float16 smem[17408];          // As[8192]+Bs[8192]; epi: 128x136
    const int tid = threadIdx.x;
    const int lane = tid & 63, wv = tid >> 6;
    const int wr = wv >> 1, wc = wv & 1;
    const int m_ = lane & 15, quad = lane >> 4;
    const int b = blockIdx.z;

    // XCD swizzle: 136 = 8 * 17 -> each XCD gets 17 consecutive pairs.
    const int swz = (blockIdx.x % 8) * 17 + blockIdx.x / 8;
    int rem = swz, ti = 0, rowlen = NN / 128;
    while (rem >= rowlen) { rem -= rowlen; ++ti; --rowlen; }
    const int tj = ti + rem;
    const int I = ti * 128, J = tj * 128;
    const bool diag = (ti == tj);

    const _Float16* Ab = xhn + ((size_t)b * NN + I) * DD;
    const _Float16* Bb = xhn + ((size_t)b * NN + J) * DD;

    f32x4 acc[4][4];
    #pragma unroll
    for (int i = 0; i < 4; ++i)
        #pragma unroll
        for (int j = 0; j < 4; ++j) acc[i][j] = (f32x4){0.f, 0.f, 0.f, 0.f};

    const int sub = lane >> 3;
    const int swc = (lane & 7) ^ sub;
    const _Float16* agl = Ab + (size_t)(wv * 32 + sub) * DD + swc * 8;
    const _Float16* bgl = Bb + (size_t)(wv * 32 + sub) * DD + swc * 8;
    _Float16* As = smem;
    _Float16* Bs = smem + 8192;

    for (int kb = 0; kb < DD / 64; ++kb) {
        const int k0 = kb * 64;
        #pragma unroll
        for (int c = 0; c < 4; ++c) {
            async_ld16(&As[(wv * 32 + c * 8) * 64], agl + (size_t)c * 8 * DD + k0);
            async_ld16(&Bs[(wv * 32 + c * 8) * 64], bgl + (size_t)c * 8 * DD + k0);
        }
        VM_WAIT(0);
        RAW_BAR();
        __builtin_amdgcn_s_setprio(1);
        #pragma unroll
        for (int kc = 0; kc < 2; ++kc) {
            f16x8 af[4], bf[4];
            #pragma unroll
            for (int t = 0; t < 4; ++t) {
                const int Ra = wr * 64 + t * 16 + m_;
                const int Rb = wc * 64 + t * 16 + m_;
                af[t] = *(const f16x8*)&As[Ra * 64 + (((kc * 4 + quad) ^ (Ra & 7)) * 8)];
                bf[t] = *(const f16x8*)&Bs[Rb * 64 + (((kc * 4 + quad) ^ (Rb & 7)) * 8)];
            }
            #pragma unroll
            for (int i = 0; i < 4; ++i)
                #pragma unroll
                for (int j = 0; j < 4; ++j)
                    acc[i][j] = __builtin_amdgcn_mfma_f32_16x16x32_f16(af[i], bf[j], acc[i][j], 0, 0, 0);
        }
        __builtin_amdgcn_s_setprio(0);
        RAW_BAR();   // all waves done reading before next stage overwrites
    }

    // Epilogue: exp into packed f16x4; register row/col sums.
    f16x4 wq[4][4];
    float rowpart[4][4];
    float colpart[4] = {0.f, 0.f, 0.f, 0.f};
    #pragma unroll
    for (int i = 0; i < 4; ++i)
        #pragma unroll
        for (int r = 0; r < 4; ++r) rowpart[i][r] = 0.f;

    #pragma unroll
    for (int i = 0; i < 4; ++i) {
        #pragma unroll
        for (int j = 0; j < 4; ++j) {
            #pragma unroll
            for (int r = 0; r < 4; ++r) {
                const float w = __expf(acc[i][j][r]);
                wq[i][j][r] = (_Float16)w;
                rowpart[i][r] += w;
                colpart[j] += w;
            }
        }
    }

    #pragma unroll
    for (int i = 0; i < 4; ++i) {
        #pragma unroll
        for (int r = 0; r < 4; ++r) {
            float s = rowpart[i][r];
            s += __shfl_xor(s, 1);
            s += __shfl_xor(s, 2);
            s += __shfl_xor(s, 4);
            s += __shfl_xor(s, 8);
            if (m_ == 0)
                atomicAdd(&denom[b * NN + I + wr * 64 + i * 16 + quad * 4 + r], s);
        }
    }
    if (!diag) {
        #pragma unroll
        for (int j = 0; j < 4; ++j) {
            float s = colpart[j];
            s += __shfl_xor(s, 16);
            s += __shfl_xor(s, 32);
            if (quad == 0)
                atomicAdd(&denom[b * NN + J + wc * 64 + j * 16 + m_], s);
        }
    }

    LGKM_BAR();   // LDS ordering only: atomics keep draining

    // Phase 1: WtT[col][row] (stride 136), b64 writes -> coalesced W(J,I).
    _Float16* WtT = smem;
    #pragma unroll
    for (int i = 0; i < 4; ++i) {
        const int rowb = wr * 64 + i * 16 + quad * 4;
        #pragma unroll
        for (int j = 0; j < 4; ++j) {
            const int col = wc * 64 + j * 16 + m_;
            *(f16x4*)&WtT[col * 136 + rowb] = wq[i][j];
        }
    }
    LGKM_BAR();
    // lane-coalesced store: 16 consecutive lanes = one contiguous 256 B row segment.
    #pragma unroll
    for (int it2 = 0; it2 < 8; ++it2) {
        const int id = it2 * 256 + tid;
        const int rr = id >> 4, off = (id & 15) * 8;
        *(uint4*)(W + ((size_t)b * NN + J + rr) * NN + I + off) =
            *(const uint4*)&WtT[rr * 136 + off];
    }
    // Phase 2 (off-diag): row-major Wt -> coalesced W(I,J).
    if (!diag) {
        LGKM_BAR();   // phase-1 LDS reads done; W(J,I) stores still in flight
        _Float16* Wt = smem;
        #pragma unroll
        for (int i = 0; i < 4; ++i) {
            const int rowb = wr * 64 + i * 16 + quad * 4;
            #pragma unroll
            for (int j = 0; j < 4; ++j) {
                const int col = wc * 64 + j * 16 + m_;
                #pragma unroll
                for (int r = 0; r < 4; ++r)
                    Wt[(rowb + r) * 136 + col] = wq[i][j][r];
            }
        }
        LGKM_BAR();
        #pragma unroll
        for (int it2 = 0; it2 < 8; ++it2) {
            const int id = it2 * 256 + tid;
            const int rr = id >> 4, off = (id & 15) * 8;
            *(uint4*)(W + ((size_t)b * NN + I + rr) * NN + J + off) =
                *(const uint4*)&Wt[rr * 136 + off];
        }
    }
}

// ---------------------------------------------------------------------------
// K3: O = (W @ V) * (1/denom_i), fp32 out.
// 256x256 tile, 8 waves 2Mx4N, BK=64, 128 KiB ring-2 dbuf, XCD batch-pin.
// NEW: fine per-phase stage interleave (m196's proven lever): stage loads
// spread 2-per-phase instead of an 8-burst at P3.
//   stage(t+1): chunks c0,c1 at P3 of tile t-1; c2 at P0(t); c3 at P1(t)
//   -> buffer (t+1)&1 is not being read during tile t, and P3 writes to
//      the current buffer only after its last ds_read (end of P2). Ring-2 safe.
// vmcnt: top of tile t waits VM_WAIT(4) (4 newest = t+1's c0,c1); last tile 0.
// ---------------------------------------------------------------------------
__global__ __launch_bounds__(512, 2) void k_pv(const _Float16* __restrict__ W,
                                               const _Float16* __restrict__ vT,
                                               const float* __restrict__ denom,
                                               float* __restrict__ out) {
    extern __shared__ _Float16 smem[];        // 2 x (A 16384 + B 16384) halves = 128 KiB
    float* rdI = (float*)(smem + 65536);      // 256 floats after the buffers
    const int tid = threadIdx.x;
    const int lane = tid & 63, w = tid >> 6;  // 8 waves
    const int wr = w >> 2, wcol = w & 3;      // 2 x 4 wave grid
    const int m_ = lane & 15, quad = lane >> 4;

    // XCD pinning: bx -> (xcd, slot); b = (slot>>4)*8 + xcd; I,d from slot.
    const int bx = blockIdx.x;
    const int xcd = bx & 7, slot = bx >> 3;
    const int b  = (slot >> 4) * 8 + xcd;
    const int I  = ((slot >> 1) & 7) * 256;
    const int D0 = (slot & 1) * 256;

    const _Float16* Ab = W  + ((size_t)b * NN + I) * NN;
    const _Float16* Bb = vT + ((size_t)b * DD + D0) * NN;

    const int sub = lane >> 3;
    const int swc = (lane & 7) ^ sub;
    const _Float16* agl = Ab + (size_t)(w * 32 + sub) * NN + swc * 8;
    const _Float16* bgl = Bb + (size_t)(w * 32 + sub) * NN + swc * 8;

    f32x4 acc[8][4];
    #pragma unroll
    for (int i = 0; i < 8; ++i)
        #pragma unroll
        for (int j = 0; j < 4; ++j) acc[i][j] = (f32x4){0.f, 0.f, 0.f, 0.f};

    f16x8 afq[4][2];   // current i-quadrant A frags (kc 0,1)
    f16x8 bfq[4][2];   // all four j B frags (kc 0,1)

    const int NT = NN / 64;

// Stage one chunk pair (A chunk c_, B chunk c_) of tile kb_ (2 vmem loads).
#define P_PART(kb_, c_) do {                                                  \
    _Float16* A_ = smem + (((kb_) & 1) << 15);                                \
    const int k0_ = (kb_) * 64;                                               \
    async_ld16(&A_[(w * 32 + (c_) * 8) * 64], agl + (size_t)(c_) * 8 * NN + k0_); \
    async_ld16(&A_[16384 + (w * 32 + (c_) * 8) * 64], bgl + (size_t)(c_) * 8 * NN + k0_); \
    } while (0)

#define LD_A(t_, ih_) do {                                                    \
    const int R = wr * 128 + ((ih_) * 4 + (t_)) * 16 + m_;                    \
    afq[t_][0] = *(const f16x8*)&As_[R * 64 + ((quad ^ (R & 7)) * 8)];        \
    afq[t_][1] = *(const f16x8*)&As_[R * 64 + (((4 + quad) ^ (R & 7)) * 8)];  \
    } while (0)

#define LD_B(j_) do {                                                         \
    const int Rb = wcol * 64 + (j_) * 16 + m_;                                \
    bfq[j_][0] = *(const f16x8*)&Bs_[Rb * 64 + ((quad ^ (Rb & 7)) * 8)];      \
    bfq[j_][1] = *(const f16x8*)&Bs_[Rb * 64 + (((4 + quad) ^ (Rb & 7)) * 8)];\
    } while (0)

#define MFMA_Q(ih_, jh_) do {                                                 \
    __builtin_amdgcn_s_setprio(1);                                            \
    _Pragma("unroll")                                                         \
    for (int t = 0; t < 4; ++t)                                               \
        _Pragma("unroll")                                                     \
        for (int j = 0; j < 2; ++j) {                                         \
            acc[(ih_)*4+t][(jh_)*2+j] = __builtin_amdgcn_mfma_f32_16x16x32_f16( \
                afq[t][0], bfq[(jh_)*2+j][0], acc[(ih_)*4+t][(jh_)*2+j], 0, 0, 0); \
            acc[(ih_)*4+t][(jh_)*2+j] = __builtin_amdgcn_mfma_f32_16x16x32_f16( \
                afq[t][1], bfq[(jh_)*2+j][1], acc[(ih_)*4+t][(jh_)*2+j], 0, 0, 0); \
        }                                                                     \
    __builtin_amdgcn_s_setprio(0);                                            \
    } while (0)

    // Prologue: steady-state image at t=0: stage(0) fully issued,
    // stage(1) chunks c0,c1 issued.
    P_PART(0, 0); P_PART(0, 1); P_PART(0, 2); P_PART(0, 3);
    P_PART(1, 0); P_PART(1, 1);

    for (int tc = 0; tc < NT; ++tc) {
        const _Float16* As_ = smem + ((tc & 1) << 15);
        const _Float16* Bs_ = As_ + 16384;
        if (tc == NT - 1) { VM_WAIT(0); } else { VM_WAIT(4); }
        RAW_BAR();
        // ---- P0: quadrant (0,0). ds: af[0..3] + bf[0..1]; stage(t+1) c2
        #pragma unroll
        for (int t = 0; t < 4; ++t) LD_A(t, 0);
        LD_B(0); LD_B(1);
        if (tc + 1 < NT) P_PART(tc + 1, 2);
        RAW_BAR();
        LGKM0_FENCE();
        MFMA_Q(0, 0);
        RAW_BAR();
        // ---- P1: quadrant (0,1). ds: bf[2..3]; stage(t+1) c3
        LD_B(2); LD_B(3);
        if (tc + 1 < NT) P_PART(tc + 1, 3);
        RAW_BAR();
        LGKM0_FENCE();
        MFMA_Q(0, 1);
        RAW_BAR();
        // ---- P2: quadrant (1,0). ds: af[4..7]
        #pragma unroll
        for (int t = 0; t < 4; ++t) LD_A(t, 1);
        RAW_BAR();
        LGKM0_FENCE();
        MFMA_Q(1, 0);
        RAW_BAR();
        // ---- P3: quadrant (1,1). current buffer's reads done -> stage(t+2) c0,c1
        if (tc + 2 < NT) { P_PART(tc + 2, 0); P_PART(tc + 2, 1); }
        RAW_BAR();
        MFMA_Q(1, 1);
        RAW_BAR();
    }

    // Epilogue: per-row reciprocal denominators via LDS broadcast, then store.
    if (tid < 256) rdI[tid] = 1.0f / denom[b * NN + I + tid];
    LGKM_BAR();

    #pragma unroll
    for (int i = 0; i < 8; ++i) {
        const int rowb = wr * 128 + i * 16 + quad * 4;
        #pragma unroll
        for (int r = 0; r < 4; ++r) {
            const float sc = rdI[rowb + r];
            float* op = out + ((size_t)(b * NN + I + rowb + r)) * DD + D0;
            #pragma unroll
            for (int j = 0; j < 4; ++j)
                op[wcol * 64 + j * 16 + m_] = acc[i][j][r] * sc;
        }
    }
#undef P_PART
#undef LD_A
#undef LD_B
#undef MFMA_Q
}

// ---------------------------------------------------------------------------
extern "C" void kernel_launch(void* const* d_in, const int* in_sizes, int n_in,
                              void* d_out, int out_size, void* d_ws, size_t ws_size,
                              hipStream_t stream) {
    const float* x = (const float*)d_in[0];
    char* ws = (char*)d_ws;
    _Float16* xhn   = (_Float16*)(ws);                        // 32 MiB normalized fp16
    _Float16* vT    = (_Float16*)(ws + (size_t)33554432);     // 32 MiB fp16 x^T
    _Float16* W     = (_Float16*)(ws + (size_t)67108864);     // 128 MiB fp16 exp-scores
    float*    denom = (float*)   (ws + (size_t)201326592);    // 128 KiB
    float*    out   = (float*)d_out;

    k_prep<<<dim3(NN / 64, BB), 256, 0, stream>>>(x, xhn, vT, denom);
    const int npairs = (NN / 128) * (NN / 128 + 1) / 2;   // 136
    k_scores<<<dim3(npairs, 1, BB), 256, 0, stream>>>(xhn, W, denom);
    // flat 256-block grid, XCD batch-pinned; 128 KiB dbuf + 1 KiB rdI dynamic
    k_pv<<<dim3(256, 1, 1), 512, 132096, stream>>>(W, vT, denom, out);
}